// Round 4
// baseline (176.042 us; speedup 1.0000x reference)
//
#include <hip/hip_runtime.h>
#include <math.h>

#define D_IN 768
#define E_DIM 256
#define NB 32
#define NP 192
#define NA 30

typedef __attribute__((ext_vector_type(8))) __bf16 bf16x8;
typedef __attribute__((ext_vector_type(4))) float f32x4;

__device__ __forceinline__ bf16x8 cvt8(float4 a, float4 b) {
    bf16x8 v;
    v[0]=(__bf16)a.x; v[1]=(__bf16)a.y; v[2]=(__bf16)a.z; v[3]=(__bf16)a.w;
    v[4]=(__bf16)b.x; v[5]=(__bf16)b.y; v[6]=(__bf16)b.z; v[7]=(__bf16)b.w;
    return v;
}

// ---------------------------------------------------------------------------
// Fused projection kernel v2: barrier-free register-resident MFMA K-loop.
// grid = 226 blocks:
//   [0,192)   : patch blocks (v = bid/6, chunk c = bid%6), 32 rows
//   [192,224) : att blocks, one per t (30 rows, rows 30/31 duplicate row 0)
//   224 / 225 : visual_embed / textual_embed (32 rows = CLS per batch)
// Wave w owns e-tiles w*4..w*4+3; both 16-row m-tiles. Per 32-k tile each lane
// gathers its A frag (2 float4 from its m-row) and 4 B frags (2 float4 from
// W e-rows), cvt->bf16, 8 MFMAs. No LDS, no barriers until the epilogue.
// Epilogue: spill acc to LDSf[32][260], row inv-norms, means, bf16 frag packs:
//   pn_frag[v][c] : l2norm(patch) A-row-frag  [mt2][koct8][lane64][8]
//   pB_frag[v][c] : raw patch B-frag (k=p)    [nt16][lane64][8]
//   an_frag[t]    : l2norm(att) row-frag      [at2][koct8][lane64][8]
//   attT_frag[t]  : raw att B-frag (k=a)      [nt16][lane64][8]
// ---------------------------------------------------------------------------
__global__ __launch_bounds__(256) void proj_fused_kernel(
    const float* __restrict__ vf, const float* __restrict__ tf,
    const float* __restrict__ Wv, const float* __restrict__ bv,
    const float* __restrict__ Wt, const float* __restrict__ bt,
    const float* __restrict__ Wp, const float* __restrict__ bp,
    const float* __restrict__ Wa, const float* __restrict__ ba,
    const int* __restrict__ att_nums,
    float* __restrict__ out_vis, float* __restrict__ out_txt,
    float* __restrict__ out_pm, float* __restrict__ out_am,
    __bf16* __restrict__ pn_frag, __bf16* __restrict__ pB_frag,
    __bf16* __restrict__ an_frag, __bf16* __restrict__ attT_frag)
{
    __shared__ float LDSf[32 * 260];
    __shared__ float invn_s[32];

    const int bid = blockIdx.x;
    const int tid = threadIdx.x;
    const int w = tid >> 6, l = tid & 63, q = l >> 4, n15 = l & 15;

    int role;  // 0 patch, 1 att, 2 vis, 3 txt
    const float *W, *bias;
    if (bid < 192)       { role = 0; W = Wp; bias = bp; }
    else if (bid < 224)  { role = 1; W = Wa; bias = ba; }
    else if (bid == 224) { role = 2; W = Wv; bias = bv; }
    else                 { role = 3; W = Wt; bias = bt; }

    // per-lane A row pointers for both m-tiles
    const float *arow0, *arow1;
    if (role == 0) {
        const int v = bid / 6, c = bid - 6 * v;
        arow0 = vf + (size_t)(v * 193 + 1 + c * 32 + n15) * D_IN;
        arow1 = arow0 + (size_t)16 * D_IN;
    } else if (role == 1) {
        const int t = bid - 192;
        const int r0 = n15;                              // 0..15 valid
        const int r1 = (16 + n15 < NA) ? 16 + n15 : 0;   // rows >=30 dup row 0
        arow0 = tf + (size_t)(t * 31 + 1 + r0) * D_IN;
        arow1 = tf + (size_t)(t * 31 + 1 + r1) * D_IN;
    } else if (role == 2) {
        arow0 = vf + (size_t)n15 * 193 * D_IN;
        arow1 = vf + (size_t)(16 + n15) * 193 * D_IN;
    } else {
        arow0 = tf + (size_t)n15 * 31 * D_IN;
        arow1 = tf + (size_t)(16 + n15) * 31 * D_IN;
    }
    // per-lane W row pointers for the 4 e-tiles this wave owns
    const float* wrow[4];
    #pragma unroll
    for (int nt = 0; nt < 4; ++nt)
        wrow[nt] = W + (size_t)((w * 4 + nt) * 16 + n15) * D_IN;

    f32x4 acc[2][4];
    #pragma unroll
    for (int m = 0; m < 2; ++m)
        #pragma unroll
        for (int n = 0; n < 4; ++n) { f32x4 z = {0.f,0.f,0.f,0.f}; acc[m][n] = z; }

    const int kq8 = q * 8;
    #pragma unroll 4
    for (int kt = 0; kt < 24; ++kt) {
        const int k0 = kt * 32 + kq8;
        float4 fa0 = *(const float4*)&arow0[k0];
        float4 fa1 = *(const float4*)&arow0[k0 + 4];
        float4 fb0 = *(const float4*)&arow1[k0];
        float4 fb1 = *(const float4*)&arow1[k0 + 4];
        bf16x8 a0 = cvt8(fa0, fa1);
        bf16x8 a1 = cvt8(fb0, fb1);
        #pragma unroll
        for (int nt = 0; nt < 4; ++nt) {
            float4 w0 = *(const float4*)&wrow[nt][k0];
            float4 w1 = *(const float4*)&wrow[nt][k0 + 4];
            bf16x8 bfr = cvt8(w0, w1);
            acc[0][nt] = __builtin_amdgcn_mfma_f32_16x16x32_bf16(a0, bfr, acc[0][nt], 0, 0, 0);
            acc[1][nt] = __builtin_amdgcn_mfma_f32_16x16x32_bf16(a1, bfr, acc[1][nt], 0, 0, 0);
        }
    }

    // ---- embeds: direct store (C-layout: row = mt*16+q*4+r, col = e) ----
    if (role >= 2) {
        float* outp = (role == 2) ? out_vis : out_txt;
        #pragma unroll
        for (int mt = 0; mt < 2; ++mt)
            #pragma unroll
            for (int nt = 0; nt < 4; ++nt) {
                const int col = (w * 4 + nt) * 16 + n15;
                const float b = bias[col];
                #pragma unroll
                for (int r = 0; r < 4; ++r) {
                    const int row = mt * 16 + q * 4 + r;
                    outp[row * E_DIM + col] = acc[mt][nt][r] + b;
                }
            }
        return;
    }

    // ---- spill acc (+bias) to LDSf[32][260] ----
    #pragma unroll
    for (int mt = 0; mt < 2; ++mt)
        #pragma unroll
        for (int nt = 0; nt < 4; ++nt) {
            const int col = (w * 4 + nt) * 16 + n15;
            const float b = bias[col];
            #pragma unroll
            for (int r = 0; r < 4; ++r)
                LDSf[(mt * 16 + q * 4 + r) * 260 + col] = acc[mt][nt][r] + b;
        }
    __syncthreads();

    if (role == 0) {
        const int v = bid / 6, c = bid - 6 * v;
        {
            const int row = tid >> 3, seg = tid & 7;
            const float* rr = &LDSf[row * 260 + seg * 32];
            float ssq = 0.f;
            #pragma unroll
            for (int j = 0; j < 32; ++j) ssq += rr[j] * rr[j];
            ssq += __shfl_xor(ssq, 1, 64);
            ssq += __shfl_xor(ssq, 2, 64);
            ssq += __shfl_xor(ssq, 4, 64);
            if (seg == 0) invn_s[row] = 1.f / fmaxf(sqrtf(ssq), 1e-12f);
        }
        {
            float s = 0.f;
            #pragma unroll
            for (int r = 0; r < 32; ++r) s += LDSf[r * 260 + tid];
            atomicAdd(&out_pm[v * E_DIM + tid], s * (1.f / 192.f));
        }
        __syncthreads();
        __bf16* dstn = pn_frag + (size_t)(v * 6 + c) * 8192;
        #pragma unroll
        for (int i = 0; i < 4; ++i) {
            const int slot = tid + 256 * i;
            const int mt = slot >> 9, koct = (slot >> 6) & 7, lane = slot & 63;
            const int prl = mt * 16 + (lane & 15);
            const int e0 = koct * 32 + (lane >> 4) * 8;
            const float inr = invn_s[prl];
            const float* src = &LDSf[prl * 260 + e0];
            bf16x8 vv;
            #pragma unroll
            for (int j = 0; j < 8; ++j) vv[j] = (__bf16)(src[j] * inr);
            *(bf16x8*)&dstn[slot * 8] = vv;
        }
        __bf16* dstb = pB_frag + (size_t)(v * 6 + c) * 8192;
        #pragma unroll
        for (int i = 0; i < 4; ++i) {
            const int slot = tid + 256 * i;
            const int nt = slot >> 6, lane = slot & 63;
            const int e = nt * 16 + (lane & 15);
            const int p0 = (lane >> 4) * 8;
            bf16x8 vv;
            #pragma unroll
            for (int j = 0; j < 8; ++j) vv[j] = (__bf16)LDSf[(p0 + j) * 260 + e];
            *(bf16x8*)&dstb[slot * 8] = vv;
        }
    } else {
        const int t = bid - 192;
        const int Av = att_nums[t];
        {
            const int row = tid >> 3, seg = tid & 7;
            const float* rr = &LDSf[row * 260 + seg * 32];
            float ssq = 0.f;
            #pragma unroll
            for (int j = 0; j < 32; ++j) ssq += rr[j] * rr[j];
            ssq += __shfl_xor(ssq, 1, 64);
            ssq += __shfl_xor(ssq, 2, 64);
            ssq += __shfl_xor(ssq, 4, 64);
            if (seg == 0) invn_s[row] = (row < NA) ? 1.f / fmaxf(sqrtf(ssq), 1e-12f) : 0.f;
        }
        {
            float s = 0.f;
            #pragma unroll
            for (int r = 0; r < NA; ++r) s += LDSf[r * 260 + tid];
            out_am[t * E_DIM + tid] = s / (float)Av;
        }
        __syncthreads();
        __bf16* dstn = an_frag + (size_t)t * 8192;
        #pragma unroll
        for (int i = 0; i < 4; ++i) {
            const int slot = tid + 256 * i;
            const int at = slot >> 9, koct = (slot >> 6) & 7, lane = slot & 63;
            const int a = at * 16 + (lane & 15);
            const int e0 = koct * 32 + (lane >> 4) * 8;
            const float inr = (a < NA) ? invn_s[a] : 0.f;
            const float* src = &LDSf[a * 260 + e0];
            bf16x8 vv;
            #pragma unroll
            for (int j = 0; j < 8; ++j) vv[j] = (__bf16)(src[j] * inr);
            *(bf16x8*)&dstn[slot * 8] = vv;
        }
        __bf16* dstb = attT_frag + (size_t)t * 8192;
        #pragma unroll
        for (int i = 0; i < 4; ++i) {
            const int slot = tid + 256 * i;
            const int nt = slot >> 6, lane = slot & 63;
            const int e = nt * 16 + (lane & 15);
            const int a0 = (lane >> 4) * 8;
            bf16x8 vv;
            #pragma unroll
            for (int j = 0; j < 8; ++j)
                vv[j] = (a0 + j < NA) ? (__bf16)LDSf[(a0 + j) * 260 + e] : (__bf16)0.f;
            *(bf16x8*)&dstb[slot * 8] = vv;
        }
    }
}

// ---------------------------------------------------------------------------
// MFMA pair kernel: one block per (v,t). All staging = contiguous 16B copies.
// ---------------------------------------------------------------------------
__global__ __launch_bounds__(256) void pair_mfma_kernel(
    const __bf16* __restrict__ pn_frag, const __bf16* __restrict__ pB_frag,
    const __bf16* __restrict__ an_frag, const __bf16* __restrict__ attT_frag,
    const int* __restrict__ att_nums, float* __restrict__ out_sim)
{
    __shared__ __align__(16) __bf16 an_s[8192];
    __shared__ __align__(16) __bf16 attT_s[8192];
    __shared__ __align__(16) __bf16 pn_s[8192];
    __shared__ __align__(16) __bf16 pB_s[8192];
    __shared__ __align__(16) __bf16 Xa_s[1024];
    __shared__ __align__(16) __bf16 XaT_s[1024];
    __shared__ float red_s[128];
    __shared__ float invn_s[32];
    __shared__ float wred_s[4];

    const int v = blockIdx.x, t = blockIdx.y;
    const int tid = threadIdx.x;
    const int w = tid >> 6, l = tid & 63, q = l >> 4, n15 = l & 15;
    const int Av = att_nums[t];

    {
        const __bf16* s1 = an_frag + (size_t)t * 8192;
        const __bf16* s2 = attT_frag + (size_t)t * 8192;
        #pragma unroll
        for (int i = 0; i < 4; ++i) {
            const int slot = tid + 256 * i;
            *(bf16x8*)&an_s[slot * 8]   = *(const bf16x8*)&s1[slot * 8];
            *(bf16x8*)&attT_s[slot * 8] = *(const bf16x8*)&s2[slot * 8];
        }
    }
    __syncthreads();

    bf16x8 ab[4];
    #pragma unroll
    for (int n = 0; n < 4; ++n)
        ab[n] = *(const bf16x8*)&attT_s[((w * 4 + n) * 64 + l) * 8];

    f32x4 apacc[2][4];
    #pragma unroll
    for (int m = 0; m < 2; ++m)
        #pragma unroll
        for (int n = 0; n < 4; ++n) { f32x4 z = {0.f,0.f,0.f,0.f}; apacc[m][n] = z; }
    float sa_acc[4] = {0.f, 0.f, 0.f, 0.f};

    for (int c = 0; c < 6; ++c) {
        __syncthreads();
        {
            const __bf16* sp1 = pn_frag + (size_t)(v * 6 + c) * 8192;
            const __bf16* sp2 = pB_frag + (size_t)(v * 6 + c) * 8192;
            #pragma unroll
            for (int i = 0; i < 4; ++i) {
                const int slot = tid + 256 * i;
                *(bf16x8*)&pn_s[slot * 8] = *(const bf16x8*)&sp1[slot * 8];
                *(bf16x8*)&pB_s[slot * 8] = *(const bf16x8*)&sp2[slot * 8];
            }
        }
        __syncthreads();

        {
            const int mt = w >> 1, at = w & 1;
            f32x4 sacc = {0.f, 0.f, 0.f, 0.f};
            #pragma unroll
            for (int kp = 0; kp < 8; ++kp) {
                bf16x8 af  = *(const bf16x8*)&pn_s[((mt * 8 + kp) * 64 + l) * 8];
                bf16x8 bf_ = *(const bf16x8*)&an_s[((at * 8 + kp) * 64 + l) * 8];
                sacc = __builtin_amdgcn_mfma_f32_16x16x32_bf16(af, bf_, sacc, 0, 0, 0);
            }
            const int a = at * 16 + n15;
            #pragma unroll
            for (int r = 0; r < 4; ++r) {
                const int pcl = q * 4 + r;
                const int pcc = mt * 16 + pcl;
                float xvv = (a < Av) ? __expf(fmaxf(20.f * sacc[r], 0.f)) : 0.f;
                __bf16 h = (__bf16)xvv;
                Xa_s[mt * 512 + (pcl + 16 * (a >> 3)) * 8 + (a & 7)] = h;
                XaT_s[at * 512 + (n15 + 16 * (pcc >> 3)) * 8 + (pcc & 7)] = h;
            }
        }
        __syncthreads();

        f32x4 aacc[2][4];
        {
            bf16x8 xa0 = *(const bf16x8*)&Xa_s[l * 8];
            bf16x8 xa1 = *(const bf16x8*)&Xa_s[512 + l * 8];
            bf16x8 xt0 = *(const bf16x8*)&XaT_s[l * 8];
            bf16x8 xt1 = *(const bf16x8*)&XaT_s[512 + l * 8];
            #pragma unroll
            for (int n = 0; n < 4; ++n) {
                f32x4 z = {0.f, 0.f, 0.f, 0.f};
                aacc[0][n] = __builtin_amdgcn_mfma_f32_16x16x32_bf16(xa0, ab[n], z, 0, 0, 0);
                aacc[1][n] = __builtin_amdgcn_mfma_f32_16x16x32_bf16(xa1, ab[n], z, 0, 0, 0);
                bf16x8 pb = *(const bf16x8*)&pB_s[((w * 4 + n) * 64 + l) * 8];
                apacc[0][n] = __builtin_amdgcn_mfma_f32_16x16x32_bf16(xt0, pb, apacc[0][n], 0, 0, 0);
                apacc[1][n] = __builtin_amdgcn_mfma_f32_16x16x32_bf16(xt1, pb, apacc[1][n], 0, 0, 0);
            }
        }

        #pragma unroll
        for (int mt2 = 0; mt2 < 2; ++mt2)
            #pragma unroll
            for (int r = 0; r < 4; ++r) {
                float ssq = 0.f;
                #pragma unroll
                for (int n = 0; n < 4; ++n) { float vv = aacc[mt2][n][r]; ssq += vv * vv; }
                ssq += __shfl_xor(ssq, 1, 64);
                ssq += __shfl_xor(ssq, 2, 64);
                ssq += __shfl_xor(ssq, 4, 64);
                ssq += __shfl_xor(ssq, 8, 64);
                if (n15 == 0) red_s[(mt2 * 16 + q * 4 + r) * 4 + w] = ssq;
            }
        __syncthreads();
        if (tid < 32) {
            float s = red_s[tid * 4] + red_s[tid * 4 + 1] + red_s[tid * 4 + 2] + red_s[tid * 4 + 3];
            invn_s[tid] = 1.f / fmaxf(sqrtf(s), 1e-12f);
        }
        __syncthreads();
        #pragma unroll
        for (int mt2 = 0; mt2 < 2; ++mt2)
            #pragma unroll
            for (int r = 0; r < 4; ++r) {
                const float inr = invn_s[mt2 * 16 + q * 4 + r];
                #pragma unroll
                for (int n = 0; n < 4; ++n) sa_acc[n] += aacc[mt2][n][r] * inr;
            }
    }

    #pragma unroll
    for (int mt2 = 0; mt2 < 2; ++mt2)
        #pragma unroll
        for (int r = 0; r < 4; ++r) {
            float ssq = 0.f;
            #pragma unroll
            for (int n = 0; n < 4; ++n) { float vv = apacc[mt2][n][r]; ssq += vv * vv; }
            ssq += __shfl_xor(ssq, 1, 64);
            ssq += __shfl_xor(ssq, 2, 64);
            ssq += __shfl_xor(ssq, 4, 64);
            ssq += __shfl_xor(ssq, 8, 64);
            if (n15 == 0) red_s[(mt2 * 16 + q * 4 + r) * 4 + w] = ssq;
        }
    __syncthreads();
    if (tid < 32) {
        float s = red_s[tid * 4] + red_s[tid * 4 + 1] + red_s[tid * 4 + 2] + red_s[tid * 4 + 3];
        invn_s[tid] = 1.f / fmaxf(sqrtf(s), 1e-12f);
    }
    __syncthreads();

    float prod = 0.f;
    #pragma unroll
    for (int n = 0; n < 4; ++n) {
        float sp = 0.f;
        #pragma unroll
        for (int mt2 = 0; mt2 < 2; ++mt2)
            #pragma unroll
            for (int r = 0; r < 4; ++r)
                sp += apacc[mt2][n][r] * invn_s[mt2 * 16 + q * 4 + r];
        float saf = sa_acc[n];
        saf += __shfl_xor(saf, 16, 64);
        saf += __shfl_xor(saf, 32, 64);
        float spf = sp;
        spf += __shfl_xor(spf, 16, 64);
        spf += __shfl_xor(spf, 32, 64);
        prod += saf * spf;
    }
    prod += __shfl_xor(prod, 1, 64);
    prod += __shfl_xor(prod, 2, 64);
    prod += __shfl_xor(prod, 4, 64);
    prod += __shfl_xor(prod, 8, 64);
    prod += __shfl_xor(prod, 16, 64);
    prod += __shfl_xor(prod, 32, 64);
    if (l == 0) wred_s[w] = prod;
    __syncthreads();
    if (tid == 0)
        out_sim[t * NB + v] = (wred_s[0] + wred_s[1] + wred_s[2] + wred_s[3]) * 0.25f
                              / ((float)Av * 30.f);
}

// ---------------------------------------------------------------------------
extern "C" void kernel_launch(void* const* d_in, const int* in_sizes, int n_in,
                              void* d_out, int out_size, void* d_ws, size_t ws_size,
                              hipStream_t stream)
{
    const float* vf = (const float*)d_in[0];
    const float* tf = (const float*)d_in[1];
    const int*   an = (const int*)d_in[3];
    const float* Wv = (const float*)d_in[4];
    const float* bv = (const float*)d_in[5];
    const float* Wt = (const float*)d_in[6];
    const float* bt = (const float*)d_in[7];
    const float* Wp = (const float*)d_in[8];
    const float* bp = (const float*)d_in[9];
    const float* Wa = (const float*)d_in[10];
    const float* ba = (const float*)d_in[11];

    float* out = (float*)d_out;
    float* out_vis = out;
    float* out_txt = out + 8192;
    float* out_pm  = out + 16384;
    float* out_am  = out + 24576;
    float* out_sim = out + 32768;

    __bf16* wsb = (__bf16*)d_ws;
    __bf16* pn_frag   = wsb;                 // 32*6*8192
    __bf16* pB_frag   = wsb + 1572864;
    __bf16* an_frag   = wsb + 3145728;       // 32*8192
    __bf16* attT_frag = wsb + 3407872;       // total 7,340,032 B

    hipMemsetAsync((char*)d_out + 16384 * sizeof(float), 0, 8192 * sizeof(float), stream);

    proj_fused_kernel<<<226, 256, 0, stream>>>(
        vf, tf, Wv, bv, Wt, bt, Wp, bp, Wa, ba, an,
        out_vis, out_txt, out_pm, out_am,
        pn_frag, pB_frag, an_frag, attT_frag);

    pair_mfma_kernel<<<dim3(NB, NB), 256, 0, stream>>>(
        pn_frag, pB_frag, an_frag, attT_frag, an, out_sim);
}